// Round 13
// baseline (877.787 us; speedup 1.0000x reference)
//
#include <hip/hip_runtime.h>

typedef unsigned short u16;
typedef __attribute__((ext_vector_type(8))) short bh8;   // 8 x bf16 (raw bits)
typedef __attribute__((ext_vector_type(4))) short bh4;   // 4 x bf16
typedef __attribute__((ext_vector_type(4))) float f4v;   // MFMA C frag

#define NN 8192
#define EE 262144
#define VDIM 256
#define EDIM 256
#define HDIM 512
#define DAMP 0.45f

__device__ __forceinline__ float b2f(u16 u){ unsigned int x = ((unsigned int)u)<<16; return __builtin_bit_cast(float, x); }
__device__ __forceinline__ u16 f2b(float f){ unsigned int x = __builtin_bit_cast(unsigned int, f); x = (x + 0x7fffu + ((x>>16)&1u)) >> 16; return (u16)x; }

__device__ __forceinline__ void gload16(const void* g, void* l){
  __builtin_amdgcn_global_load_lds((const __attribute__((address_space(1))) void*)g,
                                   (__attribute__((address_space(3))) void*)l, 16, 0, 0);
}

// ---------------- CSR build ----------------
__global__ __launch_bounds__(256) void k_hist(const int* __restrict__ src, int* __restrict__ deg){
  int e = blockIdx.x*256 + threadIdx.x;
  if (e < EE) atomicAdd(&deg[src[e]], 1);
}

__global__ __launch_bounds__(1024) void k_scan(const int* __restrict__ deg, int* __restrict__ ofs, int* __restrict__ cur){
  __shared__ int lds[1024];
  int t = threadIdx.x;
  int v[8], pre[8]; int s = 0;
  #pragma unroll
  for (int j=0;j<8;++j){ v[j] = deg[t*8+j]; }
  #pragma unroll
  for (int j=0;j<8;++j){ pre[j] = s; s += v[j]; }
  lds[t] = s; __syncthreads();
  int run = s;
  for (int off=1; off<1024; off<<=1){
    int x = (t>=off) ? lds[t-off] : 0;
    __syncthreads();
    lds[t] += x;
    __syncthreads();
  }
  int excl = lds[t] - run;
  #pragma unroll
  for (int j=0;j<8;++j){ int o = excl + pre[j]; ofs[t*8+j] = o; cur[t*8+j] = o; }
  if (t == 1023) ofs[NN] = excl + run;
}

__global__ __launch_bounds__(256) void k_permute(const int* __restrict__ src, int* __restrict__ cur,
                                                 int* __restrict__ pos, int* __restrict__ elist){
  int e = blockIdx.x*256 + threadIdx.x;
  if (e < EE){ int p = atomicAdd(&cur[src[e]], 1); pos[e] = p; elist[p] = e; }
}

// f32 -> bf16 bulk convert (8 elems/thread)
__global__ __launch_bounds__(256) void k_cvtW(const float* __restrict__ in, u16* __restrict__ out, int n8){
  int i = blockIdx.x*256 + threadIdx.x;
  if (i < n8){
    const f4v* p = (const f4v*)(in + (size_t)i*8);
    f4v f0 = p[0], f1 = p[1];
    bh8 v;
    #pragma unroll
    for (int j=0;j<4;++j){ v[j]=(short)f2b(f0[j]); v[j+4]=(short)f2b(f1[j]); }
    ((bh8*)out)[i] = v;
  }
}

// ew (f32, edge order) -> ewb (bf16, CSR order). 8 rows/block.
__global__ __launch_bounds__(256)
void k_cvtP(const float* __restrict__ ew, const int* __restrict__ pos, u16* __restrict__ ewb){
  int t = threadIdx.x;
  int row = blockIdx.x*8 + (t>>5);
  int seg = (t&31)*8;
  const f4v* p = (const f4v*)(ew + (size_t)row*256 + seg);
  f4v f0 = p[0], f1 = p[1];
  bh8 v;
  #pragma unroll
  for (int j=0;j<4;++j){ v[j]=(short)f2b(f0[j]); v[j+4]=(short)f2b(f1[j]); }
  *(bh8*)(ewb + (size_t)pos[row]*256 + seg) = v;
}

// ---------------- narrow GEMM (128x128 tile, 256 thr, 2-phase double-buffer) ----------------
// EPI 0: f32 out + bias
// EPI 3: P = exp(scale) bf16 out + per-block row-sum partials (lsum = lpart[64][NN])
// EPI 4: bf16 out, scaled by 1/lsum[row]
// EPI 6: f32 out + deg[row]*bias[col]   (S = Sew@Ww0^T + deg*bw0; ofsArg gives deg)
template<int A_BF16, int B_BF16, int EPI>
__global__ __launch_bounds__(256)
void k_gemm(const void* __restrict__ Aptr, const void* __restrict__ Bptr,
            int M, int N, int K, const float* __restrict__ bias,
            void* __restrict__ Cptr,
            const float* __restrict__ invnA, float* __restrict__ lsum,
            const int* __restrict__ ofsArg)
{
  __shared__ u16 As[2][128*32];
  __shared__ u16 Bs[2][128*32];
  __shared__ float lrow[128];
  const int t = threadIdx.x;
  const int m0 = blockIdx.y*128, n0 = blockIdx.x*128;
  const int wid = t>>6, lane = t&63, l15 = lane&15, grp = lane>>4;
  const int wm = (wid>>1)*64, wn = (wid&1)*64;
  const int srow = t>>1, shalf = t&1;
  const int rlane = lane>>2, clane = lane&3;

  if (EPI == 3 && t < 128) lrow[t] = 0.f;

  f4v acc[4][4];
  #pragma unroll
  for (int i=0;i<4;++i)
    #pragma unroll
    for (int j=0;j<4;++j) acc[i][j] = (f4v)0.0f;

  auto stage = [&](int buf, int kt){
    if (A_BF16){
      const u16* g0 = (const u16*)Aptr + (size_t)(m0 + wid*32 + rlane)*K + kt + clane*8;
      gload16(g0,                 &As[buf][wid*1024]);
      gload16(g0 + (size_t)16*K,  &As[buf][wid*1024 + 512]);
    } else {
      u16* dst = &As[buf][srow*32 + shalf*16];
      const float* ap = (const float*)Aptr + (size_t)(m0+srow)*K + kt + shalf*16;
      const f4v* ap4 = (const f4v*)ap;
      f4v f0 = ap4[0], f1 = ap4[1], f2 = ap4[2], f3 = ap4[3];
      bh8 v0, v1;
      #pragma unroll
      for (int j=0;j<4;++j){ v0[j]=(short)f2b(f0[j]); v0[j+4]=(short)f2b(f1[j]); v1[j]=(short)f2b(f2[j]); v1[j+4]=(short)f2b(f3[j]); }
      ((bh8*)dst)[0] = v0; ((bh8*)dst)[1] = v1;
    }
    if (B_BF16){
      const u16* g0 = (const u16*)Bptr + (size_t)(n0 + wid*32 + rlane)*K + kt + clane*8;
      gload16(g0,                 &Bs[buf][wid*1024]);
      gload16(g0 + (size_t)16*K,  &Bs[buf][wid*1024 + 512]);
    } else {
      u16* dst = &Bs[buf][srow*32 + shalf*16];
      const float* bp = (const float*)Bptr + (size_t)(n0+srow)*K + kt + shalf*16;
      const f4v* bp4 = (const f4v*)bp;
      f4v f0 = bp4[0], f1 = bp4[1], f2 = bp4[2], f3 = bp4[3];
      bh8 v0, v1;
      #pragma unroll
      for (int j=0;j<4;++j){ v0[j]=(short)f2b(f0[j]); v0[j+4]=(short)f2b(f1[j]); v1[j]=(short)f2b(f2[j]); v1[j+4]=(short)f2b(f3[j]); }
      ((bh8*)dst)[0] = v0; ((bh8*)dst)[1] = v1;
    }
  };

  stage(0, 0);
  __syncthreads();
  int cur = 0;
  for (int kt=0; kt<K; kt+=32){
    if (kt + 32 < K) stage(cur^1, kt+32);
    bh8 af[4], bfv[4];
    #pragma unroll
    for (int f=0; f<4; ++f) af[f]  = *(const bh8*)&As[cur][(wm + f*16 + l15)*32 + grp*8];
    #pragma unroll
    for (int f=0; f<4; ++f) bfv[f] = *(const bh8*)&Bs[cur][(wn + f*16 + l15)*32 + grp*8];
    #pragma unroll
    for (int fi=0; fi<4; ++fi)
      #pragma unroll
      for (int fj=0; fj<4; ++fj)
        acc[fi][fj] = __builtin_amdgcn_mfma_f32_16x16x32_bf16(af[fi], bfv[fj], acc[fi][fj], 0, 0, 0);
    __syncthreads();
    cur ^= 1;
  }

  if (EPI == 3){ // attention pass 1: P, partial row sums via LDS
    float ic[4];
    #pragma unroll
    for (int fj=0; fj<4; ++fj) ic[fj] = invnA[n0 + wn + fj*16 + l15];
    #pragma unroll
    for (int fi=0; fi<4; ++fi){
      #pragma unroll
      for (int r=0;r<4;++r){
        int rowg = m0 + wm + fi*16 + grp*4 + r;
        float iq = invnA[rowg];
        float rs = 0.f;
        #pragma unroll
        for (int fj=0; fj<4; ++fj){
          int c = n0 + wn + fj*16 + l15;
          float s = acc[fi][fj][r]*iq*ic[fj];
          float p = (rowg == c) ? 1.0f : __expf(s);
          ((u16*)Cptr)[(size_t)rowg*N + c] = f2b(p);
          rs += p;
        }
        rs += __shfl_xor(rs,1); rs += __shfl_xor(rs,2); rs += __shfl_xor(rs,4); rs += __shfl_xor(rs,8);
        if (l15 == 0) atomicAdd(&lrow[wm + fi*16 + grp*4 + r], rs);
      }
    }
    __syncthreads();
    if (t < 128) lsum[(size_t)blockIdx.x*NN + m0 + t] = lrow[t];
    return;
  }

  float ilv[4][4];
  if (EPI == 4){
    #pragma unroll
    for (int fi=0; fi<4; ++fi)
      #pragma unroll
      for (int r=0;r<4;++r)
        ilv[fi][r] = 1.0f / lsum[m0 + wm + fi*16 + grp*4 + r];
  }
  float degv[4][4];
  if (EPI == 6){
    #pragma unroll
    for (int fi=0; fi<4; ++fi)
      #pragma unroll
      for (int r=0;r<4;++r){
        int rowg = m0 + wm + fi*16 + grp*4 + r;
        degv[fi][r] = (float)(ofsArg[rowg+1] - ofsArg[rowg]);
      }
  }
  #pragma unroll
  for (int fj=0; fj<4; ++fj){
    int c = n0 + wn + fj*16 + l15;
    float bv = ((EPI == 0 || EPI == 6) && bias) ? bias[c] : 0.f;
    #pragma unroll
    for (int fi=0; fi<4; ++fi){
      #pragma unroll
      for (int r=0;r<4;++r){
        size_t rowg = (size_t)(m0 + wm + fi*16 + grp*4 + r);
        float v = acc[fi][fj][r];
        if (EPI == 0)      ((float*)Cptr)[rowg*N + c] = v + bv;
        else if (EPI == 6) ((float*)Cptr)[rowg*N + c] = v + degv[fi][r]*bv;
        else               ((u16*)Cptr)[rowg*N + c]  = f2b(v * ilv[fi][r]);
      }
    }
  }
}

// reduce lpart[64][NN] -> lsum[NN]
__global__ __launch_bounds__(256)
void k_lred(const float* __restrict__ lpart, float* __restrict__ lsum){
  int i = blockIdx.x*256 + threadIdx.x;
  float s = 0.f;
  #pragma unroll 8
  for (int b = 0; b < 64; ++b) s += lpart[(size_t)b*NN + i];
  lsum[i] = s;
}

// ---------------- wide edge GEMM v3 (64 x BN tile, 512 thr, A-prefetch) ----------------
// EPI 2: f32 out + c_e*rowterm + constterm, rows scattered via mapArr=elist
template<int A_BF16, int BN, int EPI>
__global__ __launch_bounds__(512, 4)
void k_gemmw3(const void* __restrict__ Aptr, const u16* __restrict__ Bptr,
              int K, const float* __restrict__ bias, void* __restrict__ Cptr,
              const int* __restrict__ mapArr, const int* __restrict__ srcIdx,
              const float* __restrict__ nsArr, const float* __restrict__ rowterm,
              const float* __restrict__ constterm)
{
  constexpr int CG = BN/64;
  constexpr int MF = (CG==8)?4:2;
  __shared__ u16 As[64*32];
  __shared__ u16 Bs[BN*32];
  const int t = threadIdx.x;
  const int tile = ((int)blockIdx.x & 7)*((int)gridDim.x>>3) + ((int)blockIdx.x>>3);
  const int m0 = tile*64;
  const int wid = t>>6, lane = t&63, l15 = lane&15, grp = lane>>4;
  const int wn = (wid & (CG-1))*64;
  const int wm = (wid / CG)*32;

  f4v acc[MF][4];
  #pragma unroll
  for (int i=0;i<MF;++i)
    #pragma unroll
    for (int j=0;j<4;++j) acc[i][j] = (f4v)0.0f;

  if (A_BF16){
    if (wid < 4){
      const u16* g0 = (const u16*)Aptr + (size_t)(m0 + wid*16 + (lane>>2))*K + (lane&3)*8;
      gload16(g0, &As[wid*512]);
    }
  } else {
    const float* ap = (const float*)Aptr + (size_t)(m0 + (t>>3))*K + (t&7)*4;
    f4v f0 = *(const f4v*)ap;
    bh4 v;
    #pragma unroll
    for (int j=0;j<4;++j) v[j]=(short)f2b(f0[j]);
    *(bh4*)&As[(t>>3)*32 + (t&7)*4] = v;
  }
  #pragma unroll
  for (int j=0;j<BN/128;++j){
    const u16* g0 = Bptr + (size_t)(j*128 + wid*16 + (lane>>2))*K + (lane&3)*8;
    gload16(g0, &Bs[wid*512 + j*4096]);
  }
  __syncthreads();

  for (int kt=0; kt<K; kt+=32){
    const bool more = (kt+32 < K);
    f4v pf; bh8 pb;
    if (more){
      if (A_BF16){
        if (t < 256)
          pb = *(const bh8*)((const u16*)Aptr + (size_t)(m0 + (t>>2))*K + kt+32 + (t&3)*8);
      } else {
        pf = *(const f4v*)((const float*)Aptr + (size_t)(m0 + (t>>3))*K + kt+32 + (t&7)*4);
      }
    }
    bh8 af[MF], bfv[4];
    #pragma unroll
    for (int f=0; f<MF; ++f) af[f]  = *(const bh8*)&As[(wm + f*16 + l15)*32 + grp*8];
    #pragma unroll
    for (int f=0; f<4; ++f)  bfv[f] = *(const bh8*)&Bs[(wn + f*16 + l15)*32 + grp*8];
    #pragma unroll
    for (int fi=0; fi<MF; ++fi)
      #pragma unroll
      for (int fj=0; fj<4; ++fj)
        acc[fi][fj] = __builtin_amdgcn_mfma_f32_16x16x32_bf16(af[fi], bfv[fj], acc[fi][fj], 0, 0, 0);
    __syncthreads();
    if (more){
      if (A_BF16){
        if (t < 256) *(bh8*)&As[(t>>2)*32 + (t&3)*8] = pb;
      } else {
        bh4 v;
        #pragma unroll
        for (int j=0;j<4;++j) v[j]=(short)f2b(pf[j]);
        *(bh4*)&As[(t>>3)*32 + (t&7)*4] = v;
      }
      #pragma unroll
      for (int j=0;j<BN/128;++j){
        const u16* g0 = Bptr + (size_t)(j*128 + wid*16 + (lane>>2))*K + kt+32 + (lane&3)*8;
        gload16(g0, &Bs[wid*512 + j*4096]);
      }
    }
    __syncthreads();
  }

  #pragma unroll
  for (int fi=0; fi<MF; ++fi){
    #pragma unroll
    for (int r=0;r<4;++r){
      int slot = m0 + wm + fi*16 + grp*4 + r;
      int mp = mapArr[slot];
      float cv = DAMP * nsArr[srcIdx[mp]];
      #pragma unroll
      for (int fj=0; fj<4; ++fj){
        int c = wn + fj*16 + l15;
        ((float*)Cptr)[(size_t)mp*BN + c] = acc[fi][fj][r] + cv*rowterm[c] + constterm[c];
      }
    }
  }
}

// ---------------- staged segment sum over ewb (CSR order, 256 cols) ----------------
__global__ __launch_bounds__(256, 8)
void k_segsumE(const u16* __restrict__ ewb, const int* __restrict__ ofs,
               float* __restrict__ Sew)
{
  __shared__ u16 lds[16*256];   // 8 KB
  const int t = threadIdx.x, w = t>>6, lane = t&63;
  const int base = blockIdx.x*128;

  int lo = 0, hi = NN-1;
  while (lo < hi){ int mid = (lo+hi+1)>>1; if (ofs[mid] <= base) lo = mid; else hi = mid-1; }
  int ni = lo;
  int nend = ofs[ni+1];

  float acc = 0.f;
  bool first = true;

  for (int chunk = 0; chunk < 8; ++chunk){
    __syncthreads();
    {
      // wave w stages rows 2w,2w+1 (pass 1) and 8+2w,8+2w+1 (pass 2)
      const u16* r0 = ewb + (size_t)(base + chunk*16 + 2*w + (lane>>5))*256 + (lane&31)*8;
      gload16(r0,                   &lds[w*512]);
      gload16(r0 + (size_t)8*256,   &lds[2048 + w*512]);
    }
    __syncthreads();
    #pragma unroll
    for (int r = 0; r < 16; ++r){
      int row = base + chunk*16 + r;
      acc += b2f(lds[r*256 + t]);
      if (row + 1 == nend){
        if (first){ atomicAdd(&Sew[(size_t)ni*256 + t], acc); first = false; }
        else        Sew[(size_t)ni*256 + t] = acc;
        acc = 0.f; ++ni;
        while (ni < NN-1 && ofs[ni+1] == row+1) ++ni;
        nend = ofs[ni+1];
      }
    }
  }
  if (base + 128 < nend) atomicAdd(&Sew[(size_t)ni*256 + t], acc);
}

// Sew f32 -> Sewb bf16
__global__ __launch_bounds__(256)
void k_cvtS(const float* __restrict__ in, u16* __restrict__ out){
  int i = blockIdx.x*256 + threadIdx.x;   // i indexes groups of 8
  const f4v* p = (const f4v*)(in + (size_t)i*8);
  f4v f0 = p[0], f1 = p[1];
  bh8 v;
  #pragma unroll
  for (int j=0;j<4;++j){ v[j]=(short)f2b(f0[j]); v[j+4]=(short)f2b(f1[j]); }
  ((bh8*)out)[i] = v;
}

// q[a] = sum_n Sew[n][a]
__global__ __launch_bounds__(256)
void k_qred(const float* __restrict__ Sew, float* __restrict__ q){
  int a = threadIdx.x;
  float s = 0.f;
  for (int n = blockIdx.x; n < NN; n += 32) s += Sew[(size_t)n*256 + a];
  atomicAdd(&q[a], s);
}

// ---------------- Gram: G = ewb^T @ ewb via MFMA with swizzled transposed LDS ----------------
// 256 blocks x 1024 rows; 8 waves, wave w computes a-strip [32w,32w+32) x all 256 b.
// Xt[c][r] stored at u16 idx c*40 + ((r + 8*((c>>4)&3)) & 31); read rotation keeps bh8 contiguous.
__global__ __launch_bounds__(512)
void k_gram(const u16* __restrict__ ewb, float* __restrict__ Gpart)
{
  __shared__ u16 Xt[256*40];   // 20 KB
  const int t = threadIdx.x, w = t>>6, lane = t&63, l15 = lane&15, grp = lane>>4;
  const int rowbase = (int)blockIdx.x * 1024;
  const int sr = t>>4, cs = t&15;

  f4v acc[2][16];
  #pragma unroll
  for (int i=0;i<2;++i)
    #pragma unroll
    for (int j=0;j<16;++j) acc[i][j] = (f4v)0.0f;

  for (int chunk = 0; chunk < 32; ++chunk){
    __syncthreads();
    #pragma unroll
    for (int i=0;i<2;++i){
      int c0 = cs*8 + i*128;
      bh8 v = *(const bh8*)(ewb + (size_t)(rowbase + chunk*32 + sr)*256 + c0);
      #pragma unroll
      for (int k=0;k<8;++k){
        int c = c0 + k;
        Xt[c*40 + ((sr + 8*((c>>4)&3)) & 31)] = (u16)v[k];
      }
    }
    __syncthreads();
    bh8 af[2];
    #pragma unroll
    for (int fa=0; fa<2; ++fa){
      int a = w*32 + fa*16 + l15;
      af[fa] = *(const bh8*)&Xt[a*40 + (((grp + (a>>4)) & 3) << 3)];
    }
    #pragma unroll
    for (int fb=0; fb<16; ++fb){
      int b = fb*16 + l15;
      bh8 bf = *(const bh8*)&Xt[b*40 + (((grp + (b>>4)) & 3) << 3)];
      #pragma unroll
      for (int fa=0; fa<2; ++fa)
        acc[fa][fb] = __builtin_amdgcn_mfma_f32_16x16x32_bf16(af[fa], bf, acc[fa][fb], 0, 0, 0);
    }
  }
  float* Gp = Gpart + (size_t)((int)blockIdx.x & 7)*65536;
  #pragma unroll
  for (int fa=0; fa<2; ++fa)
    #pragma unroll
    for (int fb=0; fb<16; ++fb)
      #pragma unroll
      for (int r=0;r<4;++r)
        atomicAdd(&Gp[(size_t)(w*32 + fa*16 + grp*4 + r)*256 + fb*16 + l15], acc[fa][fb][r]);
}

__global__ __launch_bounds__(256)
void k_gred(const float* __restrict__ Gpart, float* __restrict__ G){
  int i = blockIdx.x*256 + threadIdx.x;
  float s = 0.f;
  #pragma unroll
  for (int p=0;p<8;++p) s += Gpart[(size_t)p*65536 + i];
  G[i] = s;
}

// colsumsq[j] = Ww0[j]^T G Ww0[j] + 2 bw0[j] (q . Ww0[j]) + E bw0[j]^2
__global__ __launch_bounds__(256)
void k_csq(const float* __restrict__ G, const float* __restrict__ q,
           const float* __restrict__ Ww0, const float* __restrict__ bw0,
           float* __restrict__ colsumsq)
{
  __shared__ float wj[256];
  __shared__ float red1[256], red2[256];
  int j = blockIdx.x, a = threadIdx.x;
  wj[a] = Ww0[(size_t)j*256 + a];
  __syncthreads();
  float h = 0.f;
  #pragma unroll 8
  for (int b=0;b<256;++b) h += G[(size_t)a*256 + b]*wj[b];
  red1[a] = wj[a]*h;
  red2[a] = q[a]*wj[a];
  __syncthreads();
  for (int off=128; off>0; off>>=1){
    if (a<off){ red1[a]+=red1[a+off]; red2[a]+=red2[a+off]; }
    __syncthreads();
  }
  if (a==0){
    float b0 = bw0[j];
    colsumsq[j] = red1[0] + 2.f*b0*red2[0] + (float)EE*b0*b0;
  }
}

// ---------------- node finalize: o = out0 + DAMP*S, norms, ob ----------------
__global__ __launch_bounds__(256)
void k_nodefin2(const float* __restrict__ S, const float* __restrict__ out0,
                float* __restrict__ nsA, float* __restrict__ invn, u16* __restrict__ ob)
{
  const int t = threadIdx.x, wid = t>>6, lane = t&63;
  const int node = blockIdx.x*4 + wid;
  const f4v* s4 = (const f4v*)(S + (size_t)node*512 + lane*8);
  f4v sA = s4[0], sB = s4[1];
  const f4v* o4 = (const f4v*)(out0 + (size_t)node*512 + lane*8);
  f4v qA = o4[0], qB = o4[1];
  float o[8];
  #pragma unroll
  for (int j=0;j<4;++j){ o[j] = qA[j] + DAMP*sA[j]; o[j+4] = qB[j] + DAMP*sB[j]; }
  float nsp = 0.f, qp = 0.f;
  #pragma unroll
  for (int j=0;j<8;++j){ nsp += o[j]; qp += o[j]*o[j]; }
  #pragma unroll
  for (int m=1; m<64; m<<=1){ nsp += __shfl_xor(nsp, m); qp += __shfl_xor(qp, m); }
  if (lane == 0){ nsA[node] = nsp; invn[node] = rsqrtf(qp); }
  bh8 ub;
  #pragma unroll
  for (int j=0;j<8;++j) ub[j] = (short)f2b(o[j]);
  *(bh8*)(ob + (size_t)node*512 + lane*8) = ub;
}

__global__ __launch_bounds__(512)
void k_colred(const float* __restrict__ S, const float* __restrict__ nsA,
              const int* __restrict__ ofs,
              float* __restrict__ colsum0, float* __restrict__ cross,
              float* __restrict__ sumc, float* __restrict__ sumc2)
{
  __shared__ float red1[128], red2[128];
  const int t = threadIdx.x;
  const int n0 = blockIdx.x*128;
  float cs = 0.f, cr = 0.f;
  for (int i = 0; i < 128; ++i){
    int node = n0 + i;
    float s = S[(size_t)node*512 + t];
    cs += s; cr += nsA[node]*s;
  }
  atomicAdd(&colsum0[t], cs);
  atomicAdd(&cross[t],   DAMP*cr);
  if (t < 128){
    int node = n0 + t;
    float nsv = nsA[node];
    float degf = (float)(ofs[node+1] - ofs[node]);
    red1[t] = degf*nsv;
    red2[t] = degf*nsv*nsv;
  }
  __syncthreads();
  if (t == 0){
    float s1 = 0.f, s2 = 0.f;
    #pragma unroll 8
    for (int i = 0; i < 128; ++i){ s1 += red1[i]; s2 += red2[i]; }
    atomicAdd(sumc,  DAMP*s1);
    atomicAdd(sumc2, DAMP*DAMP*s2);
  }
}

__global__ __launch_bounds__(256)
void k_transpose(const u16* __restrict__ in, u16* __restrict__ out){
  __shared__ u16 tile[64][65];
  int r0 = blockIdx.x*64, c0 = blockIdx.y*64;
  int t = threadIdx.x;
  int rr = t>>2, cc = (t&3)*16;
  const u16* ip = in + (size_t)(r0+rr)*512 + c0 + cc;
  #pragma unroll
  for (int j=0;j<16;++j) tile[rr][cc+j] = ip[j];
  __syncthreads();
  int cr = t>>2, rb = (t&3)*16;
  u16* op = out + (size_t)(c0+cr)*8192 + r0 + rb;
  #pragma unroll
  for (int j=0;j<16;++j) op[j] = tile[rb+j][cr];
}

__global__ __launch_bounds__(512)
void k_bnfinal(const float* __restrict__ colsum0, const float* __restrict__ colsumsq,
               const float* __restrict__ cross, const float* __restrict__ sumc,
               const float* __restrict__ sumc2, const float* __restrict__ gamma,
               const float* __restrict__ beta, float* __restrict__ alphaA, float* __restrict__ bbA)
{
  int j = threadIdx.x;
  const float invE = 1.0f / (float)EE;
  float mean = (colsum0[j] + sumc[0]) * invE;
  float ex2  = (colsumsq[j] + 2.f*cross[j] + sumc2[0]) * invE;
  float var  = ex2 - mean*mean;
  float is   = rsqrtf(var + 1e-5f);
  float a    = gamma[j]*is;
  alphaA[j]  = a;
  bbA[j]     = beta[j] - mean*a;
}

// Ww1p[k][j] = alpha_j*Ww1[k][j] (f32); rowterm; constt includes bw0 fold + bw1
__global__ __launch_bounds__(512)
void k_wprime(const float* __restrict__ Ww1, const float* __restrict__ alphaA,
              const float* __restrict__ bbA, const float* __restrict__ bw1,
              const float* __restrict__ bw0,
              float* __restrict__ Ww1p, float* __restrict__ rowterm, float* __restrict__ constt)
{
  __shared__ float red[512];
  int k = blockIdx.x, j = threadIdx.x;
  float wv = Ww1[(size_t)k*512 + j];
  float a  = alphaA[j];
  Ww1p[(size_t)k*512 + j] = wv*a;
  red[j] = wv*a; __syncthreads();
  for (int off=256; off>0; off>>=1){ if (j<off) red[j] += red[j+off]; __syncthreads(); }
  if (j == 0) rowterm[k] = red[0];
  __syncthreads();
  red[j] = wv*(bbA[j] + a*bw0[j]); __syncthreads();
  for (int off=256; off>0; off>>=1){ if (j<off) red[j] += red[j+off]; __syncthreads(); }
  if (j == 0) constt[k] = red[0] + bw1[k];
}

// Wcb[k][m] = bf16( sum_j Ww1p[k][j] * Ww0[j][m] )
__global__ __launch_bounds__(256)
void k_wc(const float* __restrict__ Ww1p, const float* __restrict__ Ww0, u16* __restrict__ Wcb){
  int k = blockIdx.x, m = threadIdx.x;
  float s = 0.f;
  #pragma unroll 8
  for (int j=0;j<512;++j) s += Ww1p[(size_t)k*512+j] * Ww0[(size_t)j*256+m];
  Wcb[(size_t)k*256+m] = f2b(s);
}

// ---------------- launch ----------------
extern "C" void kernel_launch(void* const* d_in, const int* in_sizes, int n_in,
                              void* d_out, int out_size, void* d_ws, size_t ws_size,
                              hipStream_t stream)
{
  const float* x    = (const float*)d_in[0];
  const float* ew   = (const float*)d_in[1];
  const int*   ei   = (const int*)  d_in[2];
  const float* W0   = (const float*)d_in[3];
  const float* b0   = (const float*)d_in[4];
  const float* Ww0  = (const float*)d_in[5];
  const float* bw0  = (const float*)d_in[6];
  const float* W1   = (const float*)d_in[7];
  const float* b1   = (const float*)d_in[8];
  const float* Ww1  = (const float*)d_in[9];
  const float* bw1  = (const float*)d_in[10];
  const float* gamma= (const float*)d_in[11];
  const float* beta = (const float*)d_in[12];
  const int* src = ei; // edge_index[0]

  char* ws = (char*)d_ws;
  u16*   ewb   = (u16*)  (ws + 0ULL);            // [E][256] bf16, CSR order  134,217,728
  float* out0  = (float*)(ws + 134217728ULL);    // [N][512] f32
  u16*   ob    = (u16*)  (ws + 150994944ULL);    // out bf16
  u16*   obT   = (u16*)  (ws + 159383552ULL);    // out^T bf16
  u16*   onew  = (u16*)  (ws + 167772160ULL);    // mixed out bf16 (written late)
  float* Sew   = (float*)(ws + 176160768ULL);    // [N][256] f32 (zeroed)
  u16*   Sewb  = (u16*)  (ws + 184549376ULL);    // [N][256] bf16
  float* S     = (float*)(ws + 188743680ULL);    // [N][512] f32 (full write by GEMM)
  float* Gpart = (float*)(ws + 205520896ULL);    // [8][256][256] f32 (zeroed)
  float* G     = (float*)(ws + 207618048ULL);    // [256][256] f32
  float* lpart = (float*)(ws + 207880192ULL);    // [64][NN] f32
  float* lsum  = (float*)(ws + 209977344ULL);    // [NN] f32
  float* nsA   = (float*)(ws + 210010112ULL);
  float* invn  = (float*)(ws + 210042880ULL);
  int*   deg   = (int*)  (ws + 210075648ULL);
  int*   ofs   = (int*)  (ws + 210108416ULL);    // [N+1]
  int*   cur   = (int*)  (ws + 210174208ULL);
  int*   elist = (int*)  (ws + 210206976ULL);    // [E]
  float* stats = (float*)(ws + 211255552ULL);    // 4096 floats (zeroed)
  float* cross    = stats;
  float* colsum0  = stats + 512;
  float* colsumsq = stats + 1024;
  float* sumc     = stats + 1536;
  float* sumc2    = stats + 1537;
  float* qvec     = stats + 2048;                // [256]
  float* Ww1p  = (float*)(ws + 211271936ULL);    // [256][512] f32
  float* rowterm=(float*)(ws + 211796224ULL);
  float* constt =(float*)(ws + 211797248ULL);
  float* alphaA =(float*)(ws + 211798272ULL);
  float* bbA    =(float*)(ws + 211800320ULL);
  u16*   Ww0b   =(u16*)  (ws + 211802368ULL);    // [512][256] bf16
  u16*   Wcb    =(u16*)  (ws + 212064512ULL);    // [256][256] bf16
  int*   pos    = (int*)onew;                    // [E]; dead before onew written

  float* out1 = (float*)d_out;                 // [N][256]
  float* out2 = out1 + (size_t)NN*VDIM;        // [E][256]
  u16*   Pbuf = (u16*)out2;                    // P [8192][8192] bf16 (128 MiB of out2)

  hipMemsetAsync(deg, 0, NN*sizeof(int), stream);
  hipMemsetAsync(stats, 0, 16384, stream);
  hipMemsetAsync(Sew, 0, (size_t)NN*256*sizeof(float), stream);
  hipMemsetAsync(Gpart, 0, 8*65536*sizeof(float), stream);

  k_hist   <<<EE/256, 256, 0, stream>>>(src, deg);
  k_scan   <<<1, 1024, 0, stream>>>(deg, ofs, cur);
  k_permute<<<EE/256, 256, 0, stream>>>(src, cur, pos, elist);
  k_cvtW   <<<64, 256, 0, stream>>>(Ww0, Ww0b, HDIM*EDIM/8);

  // ewb = bf16(ew) in CSR order
  k_cvtP<<<EE/8, 256, 0, stream>>>(ew, pos, ewb);
  // out0 = x @ W0^T + b0
  k_gemm<0,0,0><<<dim3(4,64), 256, 0, stream>>>(x, W0, NN, HDIM, VDIM, b0, out0, nullptr, nullptr, nullptr);

  // Sew = per-node segment sums of ewb
  k_segsumE<<<2048, 256, 0, stream>>>(ewb, ofs, Sew);
  k_qred <<<32, 256, 0, stream>>>(Sew, qvec);
  k_cvtS <<<NN*256/8/256, 256, 0, stream>>>(Sew, Sewb);
  // S = Sew @ Ww0^T + deg*bw0
  k_gemm<1,1,6><<<dim3(4,64), 256, 0, stream>>>(Sewb, Ww0b, NN, HDIM, EDIM, bw0, S, nullptr, nullptr, ofs);

  k_nodefin2<<<NN/4, 256, 0, stream>>>(S, out0, nsA, invn, ob);
  k_colred <<<64, 512, 0, stream>>>(S, nsA, ofs, colsum0, cross, sumc, sumc2);

  // Gram path for colsumsq
  k_gram<<<256, 512, 0, stream>>>(ewb, Gpart);
  k_gred<<<256, 256, 0, stream>>>(Gpart, G);
  k_csq <<<HDIM, 256, 0, stream>>>(G, qvec, Ww0, bw0, colsumsq);

  k_bnfinal<<<1, 512, 0, stream>>>(colsum0, colsumsq, cross, sumc, sumc2, gamma, beta, alphaA, bbA);
  k_wprime<<<256, 512, 0, stream>>>(Ww1, alphaA, bbA, bw1, bw0, Ww1p, rowterm, constt);
  k_wc    <<<256, 256, 0, stream>>>(Ww1p, Ww0, Wcb);

  k_transpose<<<dim3(128,8), 256, 0, stream>>>(ob, obT);

  // attention pass 1 + row sums, pass 2
  k_gemm<1,1,3><<<dim3(64,64), 256, 0, stream>>>(ob, ob, NN, NN, HDIM, nullptr, Pbuf, invn, lpart, nullptr);
  k_lred<<<NN/256, 256, 0, stream>>>(lpart, lsum);
  k_gemm<1,1,4><<<dim3(4,64), 256, 0, stream>>>(Pbuf, obT, NN, HDIM, NN, nullptr, onew, nullptr, lsum, nullptr);

  // out2 = ewb @ Wcb^T + c_e*rowterm + constt (rows scattered via elist)
  k_gemmw3<1,256,2><<<4096, 512, 0, stream>>>(ewb, Wcb, EDIM, nullptr, out2,
                                              elist, src, nsA, rowterm, constt);
  // out1 = mixed_out @ W1^T + b1
  k_gemm<1,0,0><<<dim3(2,64), 256, 0, stream>>>(onew, W1, NN, VDIM, HDIM, b1, out1, nullptr, nullptr, nullptr);
}

// Round 14
// 755.872 us; speedup vs baseline: 1.1613x; 1.1613x over previous
//
#include <hip/hip_runtime.h>

typedef unsigned short u16;
typedef __attribute__((ext_vector_type(8))) short bh8;   // 8 x bf16 (raw bits)
typedef __attribute__((ext_vector_type(4))) short bh4;   // 4 x bf16
typedef __attribute__((ext_vector_type(4))) float f4v;   // MFMA C frag

#define NN 8192
#define EE 262144
#define VDIM 256
#define EDIM 256
#define HDIM 512
#define DAMP 0.45f

__device__ __forceinline__ float b2f(u16 u){ unsigned int x = ((unsigned int)u)<<16; return __builtin_bit_cast(float, x); }
__device__ __forceinline__ u16 f2b(float f){ unsigned int x = __builtin_bit_cast(unsigned int, f); x = (x + 0x7fffu + ((x>>16)&1u)) >> 16; return (u16)x; }

__device__ __forceinline__ void gload16(const void* g, void* l){
  __builtin_amdgcn_global_load_lds((const __attribute__((address_space(1))) void*)g,
                                   (__attribute__((address_space(3))) void*)l, 16, 0, 0);
}

// ---------------- CSR build ----------------
__global__ __launch_bounds__(256) void k_hist(const int* __restrict__ src, int* __restrict__ deg){
  int e = blockIdx.x*256 + threadIdx.x;
  if (e < EE) atomicAdd(&deg[src[e]], 1);
}

__global__ __launch_bounds__(1024) void k_scan(const int* __restrict__ deg, int* __restrict__ ofs, int* __restrict__ cur){
  __shared__ int lds[1024];
  int t = threadIdx.x;
  int v[8], pre[8]; int s = 0;
  #pragma unroll
  for (int j=0;j<8;++j){ v[j] = deg[t*8+j]; }
  #pragma unroll
  for (int j=0;j<8;++j){ pre[j] = s; s += v[j]; }
  lds[t] = s; __syncthreads();
  int run = s;
  for (int off=1; off<1024; off<<=1){
    int x = (t>=off) ? lds[t-off] : 0;
    __syncthreads();
    lds[t] += x;
    __syncthreads();
  }
  int excl = lds[t] - run;
  #pragma unroll
  for (int j=0;j<8;++j){ int o = excl + pre[j]; ofs[t*8+j] = o; cur[t*8+j] = o; }
  if (t == 1023) ofs[NN] = excl + run;
}

__global__ __launch_bounds__(256) void k_permute(const int* __restrict__ src, int* __restrict__ cur,
                                                 int* __restrict__ pos, int* __restrict__ elist){
  int e = blockIdx.x*256 + threadIdx.x;
  if (e < EE){ int p = atomicAdd(&cur[src[e]], 1); pos[e] = p; elist[p] = e; }
}

// f32 -> bf16 bulk convert (8 elems/thread)
__global__ __launch_bounds__(256) void k_cvtW(const float* __restrict__ in, u16* __restrict__ out, int n8){
  int i = blockIdx.x*256 + threadIdx.x;
  if (i < n8){
    const f4v* p = (const f4v*)(in + (size_t)i*8);
    f4v f0 = p[0], f1 = p[1];
    bh8 v;
    #pragma unroll
    for (int j=0;j<4;++j){ v[j]=(short)f2b(f0[j]); v[j+4]=(short)f2b(f1[j]); }
    ((bh8*)out)[i] = v;
  }
}

// ---------------- narrow GEMM (128x128 tile, 256 thr, 2-phase double-buffer) ----------------
// EPI 0: f32 out + bias
// EPI 3: P = exp(scale) bf16 out + per-block row-sum partials (lsum = lpart[64][NN])
template<int A_BF16, int B_BF16, int EPI>
__global__ __launch_bounds__(256)
void k_gemm(const void* __restrict__ Aptr, const void* __restrict__ Bptr,
            int M, int N, int K, const float* __restrict__ bias,
            void* __restrict__ Cptr,
            const float* __restrict__ invnA, float* __restrict__ lsum)
{
  __shared__ u16 As[2][128*32];
  __shared__ u16 Bs[2][128*32];
  __shared__ float lrow[128];
  const int t = threadIdx.x;
  const int m0 = blockIdx.y*128, n0 = blockIdx.x*128;
  const int wid = t>>6, lane = t&63, l15 = lane&15, grp = lane>>4;
  const int wm = (wid>>1)*64, wn = (wid&1)*64;
  const int srow = t>>1, shalf = t&1;
  const int rlane = lane>>2, clane = lane&3;

  if (EPI == 3 && t < 128) lrow[t] = 0.f;

  f4v acc[4][4];
  #pragma unroll
  for (int i=0;i<4;++i)
    #pragma unroll
    for (int j=0;j<4;++j) acc[i][j] = (f4v)0.0f;

  auto stage = [&](int buf, int kt){
    if (A_BF16){
      const u16* g0 = (const u16*)Aptr + (size_t)(m0 + wid*32 + rlane)*K + kt + clane*8;
      gload16(g0,                 &As[buf][wid*1024]);
      gload16(g0 + (size_t)16*K,  &As[buf][wid*1024 + 512]);
    } else {
      u16* dst = &As[buf][srow*32 + shalf*16];
      const float* ap = (const float*)Aptr + (size_t)(m0+srow)*K + kt + shalf*16;
      const f4v* ap4 = (const f4v*)ap;
      f4v f0 = ap4[0], f1 = ap4[1], f2 = ap4[2], f3 = ap4[3];
      bh8 v0, v1;
      #pragma unroll
      for (int j=0;j<4;++j){ v0[j]=(short)f2b(f0[j]); v0[j+4]=(short)f2b(f1[j]); v1[j]=(short)f2b(f2[j]); v1[j+4]=(short)f2b(f3[j]); }
      ((bh8*)dst)[0] = v0; ((bh8*)dst)[1] = v1;
    }
    if (B_BF16){
      const u16* g0 = (const u16*)Bptr + (size_t)(n0 + wid*32 + rlane)*K + kt + clane*8;
      gload16(g0,                 &Bs[buf][wid*1024]);
      gload16(g0 + (size_t)16*K,  &Bs[buf][wid*1024 + 512]);
    } else {
      u16* dst = &Bs[buf][srow*32 + shalf*16];
      const float* bp = (const float*)Bptr + (size_t)(n0+srow)*K + kt + shalf*16;
      const f4v* bp4 = (const f4v*)bp;
      f4v f0 = bp4[0], f1 = bp4[1], f2 = bp4[2], f3 = bp4[3];
      bh8 v0, v1;
      #pragma unroll
      for (int j=0;j<4;++j){ v0[j]=(short)f2b(f0[j]); v0[j+4]=(short)f2b(f1[j]); v1[j]=(short)f2b(f2[j]); v1[j+4]=(short)f2b(f3[j]); }
      ((bh8*)dst)[0] = v0; ((bh8*)dst)[1] = v1;
    }
  };

  stage(0, 0);
  __syncthreads();
  int cur = 0;
  for (int kt=0; kt<K; kt+=32){
    if (kt + 32 < K) stage(cur^1, kt+32);
    bh8 af[4], bfv[4];
    #pragma unroll
    for (int f=0; f<4; ++f) af[f]  = *(const bh8*)&As[cur][(wm + f*16 + l15)*32 + grp*8];
    #pragma unroll
    for (int f=0; f<4; ++f) bfv[f] = *(const bh8*)&Bs[cur][(wn + f*16 + l15)*32 + grp*8];
    #pragma unroll
    for (int fi=0; fi<4; ++fi)
      #pragma unroll
      for (int fj=0; fj<4; ++fj)
        acc[fi][fj] = __builtin_amdgcn_mfma_f32_16x16x32_bf16(af[fi], bfv[fj], acc[fi][fj], 0, 0, 0);
    __syncthreads();
    cur ^= 1;
  }

  if (EPI == 3){ // attention pass 1: P, partial row sums via LDS
    float ic[4];
    #pragma unroll
    for (int fj=0; fj<4; ++fj) ic[fj] = invnA[n0 + wn + fj*16 + l15];
    #pragma unroll
    for (int fi=0; fi<4; ++fi){
      #pragma unroll
      for (int r=0;r<4;++r){
        int rowg = m0 + wm + fi*16 + grp*4 + r;
        float iq = invnA[rowg];
        float rs = 0.f;
        #pragma unroll
        for (int fj=0; fj<4; ++fj){
          int c = n0 + wn + fj*16 + l15;
          float s = acc[fi][fj][r]*iq*ic[fj];
          float p = (rowg == c) ? 1.0f : __expf(s);
          ((u16*)Cptr)[(size_t)rowg*N + c] = f2b(p);
          rs += p;
        }
        rs += __shfl_xor(rs,1); rs += __shfl_xor(rs,2); rs += __shfl_xor(rs,4); rs += __shfl_xor(rs,8);
        if (l15 == 0) atomicAdd(&lrow[wm + fi*16 + grp*4 + r], rs);
      }
    }
    __syncthreads();
    if (t < 128) lsum[(size_t)blockIdx.x*NN + m0 + t] = lrow[t];
    return;
  }

  #pragma unroll
  for (int fj=0; fj<4; ++fj){
    int c = n0 + wn + fj*16 + l15;
    float bv = (bias) ? bias[c] : 0.f;
    #pragma unroll
    for (int fi=0; fi<4; ++fi){
      #pragma unroll
      for (int r=0;r<4;++r){
        size_t rowg = (size_t)(m0 + wm + fi*16 + grp*4 + r);
        ((float*)Cptr)[rowg*N + c] = acc[fi][fj][r] + bv;
      }
    }
  }
}

// reduce lpart[64][NN] -> lsum[NN]
__global__ __launch_bounds__(256)
void k_lred(const float* __restrict__ lpart, float* __restrict__ lsum){
  int i = blockIdx.x*256 + threadIdx.x;
  float s = 0.f;
  #pragma unroll 8
  for (int b = 0; b < 64; ++b) s += lpart[(size_t)b*NN + i];
  lsum[i] = s;
}

// ---------------- P @ V, 512 thr / 8 waves, XCD-chunked swizzle ----------------
// onew[m][c] = (P[m,:] @ obT[c,:]) / lsum[m].  Tile 128x128, grid 256 linear.
// Wave tile 32x64: wm=(wid>>1)*32, wn=(wid&1)*64. 2 waves/SIMD for latency overlap.
__global__ __launch_bounds__(512, 2)
void k_pv512(const u16* __restrict__ P, const u16* __restrict__ obT,
             const float* __restrict__ lsum, u16* __restrict__ onew)
{
  __shared__ u16 As[2][128*32];
  __shared__ u16 Bs[2][128*32];
  const int t = threadIdx.x;
  const int bid = (int)blockIdx.x;
  const int tile = (bid & 7)*32 + (bid >> 3);      // chunk 32 tiles per XCD
  const int m0 = (tile >> 2)*128, n0 = (tile & 3)*128;
  const int wid = t>>6, lane = t&63, l15 = lane&15, grp = lane>>4;
  const int wm = (wid>>1)*32, wn = (wid&1)*64;
  const int srow = t>>2, sseg = t&3;               // 1 gload16/thread per tile

  f4v acc[2][4];
  #pragma unroll
  for (int i=0;i<2;++i)
    #pragma unroll
    for (int j=0;j<4;++j) acc[i][j] = (f4v)0.0f;

  auto stage = [&](int buf, int kt){
    const u16* gA = P   + (size_t)(m0 + srow)*NN + kt + sseg*8;
    gload16(gA, &As[buf][wid*512]);
    const u16* gB = obT + (size_t)(n0 + srow)*NN + kt + sseg*8;
    gload16(gB, &Bs[buf][wid*512]);
  };

  stage(0, 0);
  __syncthreads();
  int cur = 0;
  for (int kt=0; kt<NN; kt+=32){
    if (kt + 32 < NN) stage(cur^1, kt+32);
    bh8 af[2], bfv[4];
    #pragma unroll
    for (int f=0; f<2; ++f) af[f]  = *(const bh8*)&As[cur][(wm + f*16 + l15)*32 + grp*8];
    #pragma unroll
    for (int f=0; f<4; ++f) bfv[f] = *(const bh8*)&Bs[cur][(wn + f*16 + l15)*32 + grp*8];
    #pragma unroll
    for (int fi=0; fi<2; ++fi)
      #pragma unroll
      for (int fj=0; fj<4; ++fj)
        acc[fi][fj] = __builtin_amdgcn_mfma_f32_16x16x32_bf16(af[fi], bfv[fj], acc[fi][fj], 0, 0, 0);
    __syncthreads();
    cur ^= 1;
  }

  #pragma unroll
  for (int fi=0; fi<2; ++fi){
    #pragma unroll
    for (int r=0;r<4;++r){
      int rowg = m0 + wm + fi*16 + grp*4 + r;
      float il = 1.0f / lsum[rowg];
      #pragma unroll
      for (int fj=0; fj<4; ++fj){
        int c = n0 + wn + fj*16 + l15;
        onew[(size_t)rowg*HDIM + c] = f2b(acc[fi][fj][r] * il);
      }
    }
  }
}

// ---------------- wide edge GEMM v3 (64 x BN tile, 512 thr, A-prefetch) ----------------
template<int A_BF16, int BN, int EPI>
__global__ __launch_bounds__(512, 4)
void k_gemmw3(const void* __restrict__ Aptr, const u16* __restrict__ Bptr,
              int K, const float* __restrict__ bias, void* __restrict__ Cptr,
              const int* __restrict__ mapArr, const int* __restrict__ srcIdx,
              const float* __restrict__ nsArr, const float* __restrict__ rowterm,
              const float* __restrict__ constterm)
{
  constexpr int CG = BN/64;
  constexpr int MF = (CG==8)?4:2;
  __shared__ u16 As[64*32];
  __shared__ u16 Bs[BN*32];
  const int t = threadIdx.x;
  const int tile = ((int)blockIdx.x & 7)*((int)gridDim.x>>3) + ((int)blockIdx.x>>3);
  const int m0 = tile*64;
  const int wid = t>>6, lane = t&63, l15 = lane&15, grp = lane>>4;
  const int wn = (wid & (CG-1))*64;
  const int wm = (wid / CG)*32;

  f4v acc[MF][4];
  #pragma unroll
  for (int i=0;i<MF;++i)
    #pragma unroll
    for (int j=0;j<4;++j) acc[i][j] = (f4v)0.0f;

  if (A_BF16){
    if (wid < 4){
      const u16* g0 = (const u16*)Aptr + (size_t)(m0 + wid*16 + (lane>>2))*K + (lane&3)*8;
      gload16(g0, &As[wid*512]);
    }
  } else {
    const float* ap = (const float*)Aptr + (size_t)(m0 + (t>>3))*K + (t&7)*4;
    f4v f0 = *(const f4v*)ap;
    bh4 v;
    #pragma unroll
    for (int j=0;j<4;++j) v[j]=(short)f2b(f0[j]);
    *(bh4*)&As[(t>>3)*32 + (t&7)*4] = v;
  }
  #pragma unroll
  for (int j=0;j<BN/128;++j){
    const u16* g0 = Bptr + (size_t)(j*128 + wid*16 + (lane>>2))*K + (lane&3)*8;
    gload16(g0, &Bs[wid*512 + j*4096]);
  }
  __syncthreads();

  for (int kt=0; kt<K; kt+=32){
    const bool more = (kt+32 < K);
    f4v pf; bh8 pb;
    if (more){
      if (A_BF16){
        if (t < 256)
          pb = *(const bh8*)((const u16*)Aptr + (size_t)(m0 + (t>>2))*K + kt+32 + (t&3)*8);
      } else {
        pf = *(const f4v*)((const float*)Aptr + (size_t)(m0 + (t>>3))*K + kt+32 + (t&7)*4);
      }
    }
    bh8 af[MF], bfv[4];
    #pragma unroll
    for (int f=0; f<MF; ++f) af[f]  = *(const bh8*)&As[(wm + f*16 + l15)*32 + grp*8];
    #pragma unroll
    for (int f=0; f<4; ++f)  bfv[f] = *(const bh8*)&Bs[(wn + f*16 + l15)*32 + grp*8];
    #pragma unroll
    for (int fi=0; fi<MF; ++fi)
      #pragma unroll
      for (int fj=0; fj<4; ++fj)
        acc[fi][fj] = __builtin_amdgcn_mfma_f32_16x16x32_bf16(af[fi], bfv[fj], acc[fi][fj], 0, 0, 0);
    __syncthreads();
    if (more){
      if (A_BF16){
        if (t < 256) *(bh8*)&As[(t>>2)*32 + (t&3)*8] = pb;
      } else {
        bh4 v;
        #pragma unroll
        for (int j=0;j<4;++j) v[j]=(short)f2b(pf[j]);
        *(bh4*)&As[(t>>3)*32 + (t&7)*4] = v;
      }
      #pragma unroll
      for (int j=0;j<BN/128;++j){
        const u16* g0 = Bptr + (size_t)(j*128 + wid*16 + (lane>>2))*K + kt+32 + (lane&3)*8;
        gload16(g0, &Bs[wid*512 + j*4096]);
      }
    }
    __syncthreads();
  }

  #pragma unroll
  for (int fi=0; fi<MF; ++fi){
    #pragma unroll
    for (int r=0;r<4;++r){
      int slot = m0 + wm + fi*16 + grp*4 + r;
      int mp = mapArr[slot];
      float cv = (EPI == 2) ? DAMP * nsArr[srcIdx[mp]] : 0.f;
      #pragma unroll
      for (int fj=0; fj<4; ++fj){
        int c = wn + fj*16 + l15;
        if (EPI == 5) ((u16*)Cptr)[(size_t)mp*BN + c]  = f2b(acc[fi][fj][r] + bias[c]);
        else          ((float*)Cptr)[(size_t)mp*BN + c] = acc[fi][fj][r] + cv*rowterm[c] + constterm[c];
      }
    }
  }
}

// ---------------- staged segment sum: block owns 128 CSR rows, thread owns 1 col ----------------
__global__ __launch_bounds__(512, 8)
void k_segsumB(const u16* __restrict__ w0, const int* __restrict__ ofs,
               float* __restrict__ S, float* __restrict__ sqpart)
{
  __shared__ u16 lds[16*512];
  const int t = threadIdx.x, w = t>>6, lane = t&63;
  const int base = blockIdx.x*128;

  int lo = 0, hi = NN-1;
  while (lo < hi){ int mid = (lo+hi+1)>>1; if (ofs[mid] <= base) lo = mid; else hi = mid-1; }
  int ni = lo;
  int nend = ofs[ni+1];

  float acc = 0.f, sqv = 0.f;
  bool first = true;

  for (int chunk = 0; chunk < 8; ++chunk){
    __syncthreads();
    {
      const u16* r0 = w0 + (size_t)(base + chunk*16 + w)*512 + lane*8;
      gload16(r0,                  &lds[w*512]);
      gload16(r0 + (size_t)8*512,  &lds[(w+8)*512]);
    }
    __syncthreads();
    #pragma unroll
    for (int r = 0; r < 16; ++r){
      int row = base + chunk*16 + r;
      float v = b2f(lds[r*512 + t]);
      acc += v; sqv += v*v;
      if (row + 1 == nend){
        if (first){ atomicAdd(&S[(size_t)ni*512 + t], acc); first = false; }
        else        S[(size_t)ni*512 + t] = acc;
        acc = 0.f; ++ni;
        while (ni < NN-1 && ofs[ni+1] == row+1) ++ni;
        nend = ofs[ni+1];
      }
    }
  }
  if (base + 128 < nend) atomicAdd(&S[(size_t)ni*512 + t], acc);
  sqpart[(size_t)blockIdx.x*512 + t] = sqv;
}

__global__ __launch_bounds__(512)
void k_sqred(const float* __restrict__ sqpart, float* __restrict__ colsumsq){
  int t = threadIdx.x;
  float s = 0.f;
  for (int b = 0; b < 32; ++b)
    s += sqpart[(size_t)(blockIdx.x*32 + b)*512 + t];
  atomicAdd(&colsumsq[t], s);
}

__global__ __launch_bounds__(256)
void k_nodefin2(const float* __restrict__ S, const float* __restrict__ out0,
                float* __restrict__ nsA, float* __restrict__ invn, u16* __restrict__ ob)
{
  const int t = threadIdx.x, wid = t>>6, lane = t&63;
  const int node = blockIdx.x*4 + wid;
  const f4v* s4 = (const f4v*)(S + (size_t)node*512 + lane*8);
  f4v sA = s4[0], sB = s4[1];
  const f4v* o4 = (const f4v*)(out0 + (size_t)node*512 + lane*8);
  f4v qA = o4[0], qB = o4[1];
  float o[8];
  #pragma unroll
  for (int j=0;j<4;++j){ o[j] = qA[j] + DAMP*sA[j]; o[j+4] = qB[j] + DAMP*sB[j]; }
  float nsp = 0.f, qp = 0.f;
  #pragma unroll
  for (int j=0;j<8;++j){ nsp += o[j]; qp += o[j]*o[j]; }
  #pragma unroll
  for (int m=1; m<64; m<<=1){ nsp += __shfl_xor(nsp, m); qp += __shfl_xor(qp, m); }
  if (lane == 0){ nsA[node] = nsp; invn[node] = rsqrtf(qp); }
  bh8 ub;
  #pragma unroll
  for (int j=0;j<8;++j) ub[j] = (short)f2b(o[j]);
  *(bh8*)(ob + (size_t)node*512 + lane*8) = ub;
}

__global__ __launch_bounds__(512)
void k_colred(const float* __restrict__ S, const float* __restrict__ nsA,
              const int* __restrict__ ofs,
              float* __restrict__ colsum0, float* __restrict__ cross,
              float* __restrict__ sumc, float* __restrict__ sumc2)
{
  __shared__ float red1[128], red2[128];
  const int t = threadIdx.x;
  const int n0 = blockIdx.x*128;
  float cs = 0.f, cr = 0.f;
  for (int i = 0; i < 128; ++i){
    int node = n0 + i;
    float s = S[(size_t)node*512 + t];
    cs += s; cr += nsA[node]*s;
  }
  atomicAdd(&colsum0[t], cs);
  atomicAdd(&cross[t],   DAMP*cr);
  if (t < 128){
    int node = n0 + t;
    float nsv = nsA[node];
    float degf = (float)(ofs[node+1] - ofs[node]);
    red1[t] = degf*nsv;
    red2[t] = degf*nsv*nsv;
  }
  __syncthreads();
  if (t == 0){
    float s1 = 0.f, s2 = 0.f;
    #pragma unroll 8
    for (int i = 0; i < 128; ++i){ s1 += red1[i]; s2 += red2[i]; }
    atomicAdd(sumc,  DAMP*s1);
    atomicAdd(sumc2, DAMP*DAMP*s2);
  }
}

__global__ __launch_bounds__(256)
void k_transpose(const u16* __restrict__ in, u16* __restrict__ out){
  __shared__ u16 tile[64][65];
  int r0 = blockIdx.x*64, c0 = blockIdx.y*64;
  int t = threadIdx.x;
  int rr = t>>2, cc = (t&3)*16;
  const u16* ip = in + (size_t)(r0+rr)*512 + c0 + cc;
  #pragma unroll
  for (int j=0;j<16;++j) tile[rr][cc+j] = ip[j];
  __syncthreads();
  int cr = t>>2, rb = (t&3)*16;
  u16* op = out + (size_t)(c0+cr)*8192 + r0 + rb;
  #pragma unroll
  for (int j=0;j<16;++j) op[j] = tile[rb+j][cr];
}

__global__ __launch_bounds__(512)
void k_bnfinal(const float* __restrict__ colsum0, const float* __restrict__ colsumsq,
               const float* __restrict__ cross, const float* __restrict__ sumc,
               const float* __restrict__ sumc2, const float* __restrict__ gamma,
               const float* __restrict__ beta, float* __restrict__ alphaA, float* __restrict__ bbA)
{
  int j = threadIdx.x;
  const float invE = 1.0f / (float)EE;
  float mean = (colsum0[j] + sumc[0]) * invE;
  float ex2  = (colsumsq[j] + 2.f*cross[j] + sumc2[0]) * invE;
  float var  = ex2 - mean*mean;
  float is   = rsqrtf(var + 1e-5f);
  float a    = gamma[j]*is;
  alphaA[j]  = a;
  bbA[j]     = beta[j] - mean*a;
}

__global__ __launch_bounds__(512)
void k_wprime(const float* __restrict__ Ww1, const float* __restrict__ alphaA,
              const float* __restrict__ bbA, const float* __restrict__ bw1,
              u16* __restrict__ Ww1pb, float* __restrict__ rowterm, float* __restrict__ constt)
{
  __shared__ float red[512];
  int k = blockIdx.x, j = threadIdx.x;
  float wv = Ww1[(size_t)k*512 + j];
  float a  = alphaA[j];
  Ww1pb[(size_t)k*512 + j] = f2b(wv*a);
  red[j] = wv*a; __syncthreads();
  for (int off=256; off>0; off>>=1){ if (j<off) red[j] += red[j+off]; __syncthreads(); }
  if (j == 0) rowterm[k] = red[0];
  __syncthreads();
  red[j] = wv*bbA[j]; __syncthreads();
  for (int off=256; off>0; off>>=1){ if (j<off) red[j] += red[j+off]; __syncthreads(); }
  if (j == 0) constt[k] = red[0] + bw1[k];
}

// ---------------- launch ----------------
extern "C" void kernel_launch(void* const* d_in, const int* in_sizes, int n_in,
                              void* d_out, int out_size, void* d_ws, size_t ws_size,
                              hipStream_t stream)
{
  const float* x    = (const float*)d_in[0];
  const float* ew   = (const float*)d_in[1];
  const int*   ei   = (const int*)  d_in[2];
  const float* W0   = (const float*)d_in[3];
  const float* b0   = (const float*)d_in[4];
  const float* Ww0  = (const float*)d_in[5];
  const float* bw0  = (const float*)d_in[6];
  const float* W1   = (const float*)d_in[7];
  const float* b1   = (const float*)d_in[8];
  const float* Ww1  = (const float*)d_in[9];
  const float* bw1  = (const float*)d_in[10];
  const float* gamma= (const float*)d_in[11];
  const float* beta = (const float*)d_in[12];
  const int* src = ei; // edge_index[0]

  char* ws = (char*)d_ws;
  u16*   w0    = (u16*)  (ws + 0ULL);            // [E][512] bf16, CSR-permuted rows
  float* out0  = (float*)(ws + 268435456ULL);    // [N][512] f32
  u16*   ob    = (u16*)  (ws + 285212672ULL);    // out bf16
  u16*   obT   = (u16*)  (ws + 293601280ULL);    // out^T bf16
  u16*   onew  = (u16*)  (ws + 301989888ULL);    // mixed out bf16 (written late)
  float* nsA   = (float*)(ws + 310378496ULL);    // [N]
  float* invn  = (float*)(ws + 310411264ULL);    // [N]
  int*   deg   = (int*)  (ws + 310444032ULL);    // [N]
  int*   ofs   = (int*)  (ws + 310476800ULL);    // [N+1]
  int*   cur   = (int*)  (ws + 310509824ULL);    // [N]
  int*   elist = (int*)  (ws + 310542592ULL);    // [E] int
  float* stats = (float*)(ws + 311591168ULL);    // 4096 floats zeroed
  float* cross    = stats;
  float* colsum0  = stats + 512;
  float* colsumsq = stats + 1024;
  float* sumc     = stats + 1536;
  float* sumc2    = stats + 1537;
  float* lsum   = (float*)(ws + 311607552ULL);   // [N] f32 rowsums
  u16*   Ww1pb  = (u16*)  (ws + 311640320ULL);   // [256][512] bf16
  float* rowterm= (float*)(ws + 312164608ULL);   // [256]
  float* constt = (float*)(ws + 312165632ULL);   // [256]
  float* alphaA = (float*)(ws + 312166656ULL);   // [512]
  float* bbA    = (float*)(ws + 312168704ULL);   // [512]
  u16*   Ww0b   = (u16*)  (ws + 312170752ULL);   // [512][256] bf16
  int*   pos   = (int*)onew;      // [E] int; dead before onew is written

  float* out1 = (float*)d_out;                 // [N][256]
  float* out2 = out1 + (size_t)NN*VDIM;        // [E][256] (256 MiB region)
  u16*   Pbuf = (u16*)out2;                    // P [8192][8192] bf16 (first 128 MiB)
  float* lpart  = (float*)((char*)out2 + 167772160ULL); // [64][NN] f32, 2 MiB
  float* sqpart = (float*)((char*)out2 + 247463936ULL); // [2048][512] f32, 4 MiB
  float* S      = (float*)((char*)out2 + 251658240ULL); // [N][512] f32, 16 MiB

  hipMemsetAsync(deg, 0, NN*sizeof(int), stream);
  hipMemsetAsync(stats, 0, 16384, stream);
  hipMemsetAsync(S, 0, (size_t)NN*512*sizeof(float), stream);

  k_hist   <<<EE/256, 256, 0, stream>>>(src, deg);
  k_scan   <<<1, 1024, 0, stream>>>(deg, ofs, cur);
  k_permute<<<EE/256, 256, 0, stream>>>(src, cur, pos, elist);
  k_cvtW   <<<64, 256, 0, stream>>>(Ww0, Ww0b, HDIM*EDIM/8);

  // w = ew @ Ww0^T + bw0 -> bf16, rows scatter-written to CSR order
  k_gemmw3<0,512,5><<<4096, 512, 0, stream>>>(ew, Ww0b, EDIM, bw0, w0,
                                              pos, nullptr, nullptr, nullptr, nullptr);
  // out0 = x @ W0^T + b0 -> f32
  k_gemm<0,0,0><<<dim3(4,64), 256, 0, stream>>>(x, W0, NN, HDIM, VDIM, b0, out0, nullptr, nullptr);

  // staged streaming segment sum -> S, sqpart
  k_segsumB<<<2048, 512, 0, stream>>>(w0, ofs, S, sqpart);
  k_sqred  <<<64, 512, 0, stream>>>(sqpart, colsumsq);
  k_nodefin2<<<NN/4, 256, 0, stream>>>(S, out0, nsA, invn, ob);
  k_colred <<<64, 512, 0, stream>>>(S, nsA, ofs, colsum0, cross, sumc, sumc2);

  k_transpose<<<dim3(128,8), 256, 0, stream>>>(ob, obT);
  k_bnfinal<<<1, 512, 0, stream>>>(colsum0, colsumsq, cross, sumc, sumc2, gamma, beta, alphaA, bbA);
  k_wprime<<<256, 512, 0, stream>>>(Ww1, alphaA, bbA, bw1, Ww1pb, rowterm, constt);

  // attention pass 1: P = exp(cos-sim - eye), per-block row-sum partials -> lpart
  k_gemm<1,1,3><<<dim3(64,64), 256, 0, stream>>>(ob, ob, NN, NN, HDIM, nullptr, Pbuf, invn, lpart);
  k_lred<<<NN/256, 256, 0, stream>>>(lpart, lsum);
  // attention pass 2: onew = (P @ V) / lsum   (512-thr, XCD-chunked)
  k_pv512<<<256, 512, 0, stream>>>(Pbuf, obT, lsum, onew);

  // out2 = w0 @ (alpha*Ww1)^T + c_e*rowterm + constt, rows scattered via elist
  k_gemmw3<1,256,2><<<4096, 512, 0, stream>>>(w0, Ww1pb, HDIM, nullptr, out2,
                                              elist, src, nsA, rowterm, constt);
  // out1 = mixed_out @ W1^T + b1
  k_gemm<1,0,0><<<dim3(2,64), 256, 0, stream>>>(onew, W1, NN, VDIM, HDIM, b1, out1, nullptr, nullptr);
}